// Round 14
// baseline (171.091 us; speedup 1.0000x reference)
//
#include <hip/hip_runtime.h>

typedef unsigned char u8;
typedef signed char s8;
typedef unsigned int u32;
typedef __attribute__((ext_vector_type(4))) int i32x4;

#define M_TOK 8192
#define N_OUT 4096
#define K_IN  4096
#define NT    32          // K-tiles of BK=128 int8

// ---------------------------------------------------------------------------
// Fused pre-pass (2560 blocks):
//   blocks [0,2048):    wave-per-row absmax quantize x fp32->int8 (4 rows/blk)
//   blocks [2048,2560): unpack int4 (byte-per-int32) -> int8 [O][I]
// ---------------------------------------------------------------------------
static __device__ __forceinline__ u32 pack4(float4 v, float inv) {
    int q0 = __float2int_rn(v.x * inv) & 255;
    int q1 = __float2int_rn(v.y * inv) & 255;
    int q2 = __float2int_rn(v.z * inv) & 255;
    int q3 = __float2int_rn(v.w * inv) & 255;
    return (u32)q0 | ((u32)q1 << 8) | ((u32)q2 << 16) | ((u32)q3 << 24);
}

__global__ __launch_bounds__(256) void prep_kernel(const float* __restrict__ x,
                                                   const int* __restrict__ pw,
                                                   s8* __restrict__ xq,
                                                   float* __restrict__ sx,
                                                   s8* __restrict__ wq) {
    int bid = blockIdx.x;
    int t = threadIdx.x;
    if (bid < 2048) {
        int row = bid * 4 + (t >> 6);
        int ln = t & 63;
        const float4* xr = (const float4*)(x + (size_t)row * K_IN);
        float4 v[16];
        float am = 0.f;
#pragma unroll
        for (int j = 0; j < 16; ++j) {
            v[j] = xr[ln + j * 64];
            am = fmaxf(am, fmaxf(fmaxf(fabsf(v[j].x), fabsf(v[j].y)),
                                 fmaxf(fabsf(v[j].z), fabsf(v[j].w))));
        }
#pragma unroll
        for (int o = 32; o > 0; o >>= 1) am = fmaxf(am, __shfl_xor(am, o));
        float inv = (am > 0.f) ? 127.f / am : 0.f;
        if (ln == 0) sx[row] = (am > 0.f) ? am / 127.f : 0.f;
        u32* out = (u32*)(xq + (size_t)row * K_IN);
#pragma unroll
        for (int j = 0; j < 16; ++j) out[ln + j * 64] = pack4(v[j], inv);
    } else {
        const int n4 = (N_OUT * K_IN / 2) / 4;
        int idx = (bid - 2048) * 256 + t;
        const int stride = 512 * 256;
        for (int i = idx; i < n4; i += stride) {
            int4 p = *(const int4*)(pw + (size_t)i * 4);
            u32 lo = (u32)(((p.x & 15) - 8) & 255)
                   | ((u32)((((p.x >> 4) & 15) - 8) & 255) << 8)
                   | ((u32)((((p.y) & 15) - 8) & 255) << 16)
                   | ((u32)((((p.y >> 4) & 15) - 8) & 255) << 24);
            u32 hi = (u32)(((p.z & 15) - 8) & 255)
                   | ((u32)((((p.z >> 4) & 15) - 8) & 255) << 8)
                   | ((u32)((((p.w) & 15) - 8) & 255) << 16)
                   | ((u32)((((p.w >> 4) & 15) - 8) & 255) << 24);
            uint2 o; o.x = lo; o.y = hi;
            *(uint2*)(wq + (size_t)i * 8) = o;
        }
    }
}

// ---------------------------------------------------------------------------
// 256x256 int8 GEMM, round-9/13 schedule, 2 M-tiles per block (shared B panel):
// 256 blocks, each runs two K-loop passes (bm0, bm0+1) over the same bn.
// Pass-2 prologue DMAs are issued before pass-1's epilogue (latency hidden
// under C-stores). K-loop byte-identical to the validated round-13 kernel.
// C[n][o] = sx[n] * scale[o] * sum_k xq[n][k]*wq[o][k]
// LDS: row-major [256][128] i8 per region, byte ^= (row&7)<<4 swizzle.
// ---------------------------------------------------------------------------
#define MFMA(a, b, c) __builtin_amdgcn_mfma_i32_16x16x64_i8(a, b, c, 0, 0, 0)

static __device__ __forceinline__ i32x4 ldsv(const u8* p, int idx) {
    return *(const i32x4*)(p + idx);
}

#define MFMA16(A00, A01, A10, A11, M0, M1)                \
    acc[M0][0] = MFMA(A00, b00, acc[M0][0]);              \
    acc[M0][1] = MFMA(A00, b10, acc[M0][1]);              \
    acc[M0][2] = MFMA(A00, b20, acc[M0][2]);              \
    acc[M0][3] = MFMA(A00, b30, acc[M0][3]);              \
    acc[M1][0] = MFMA(A10, b00, acc[M1][0]);              \
    acc[M1][1] = MFMA(A10, b10, acc[M1][1]);              \
    acc[M1][2] = MFMA(A10, b20, acc[M1][2]);              \
    acc[M1][3] = MFMA(A10, b30, acc[M1][3]);              \
    acc[M0][0] = MFMA(A01, b01, acc[M0][0]);              \
    acc[M0][1] = MFMA(A01, b11, acc[M0][1]);              \
    acc[M0][2] = MFMA(A01, b21, acc[M0][2]);              \
    acc[M0][3] = MFMA(A01, b31, acc[M0][3]);              \
    acc[M1][0] = MFMA(A11, b01, acc[M1][0]);              \
    acc[M1][1] = MFMA(A11, b11, acc[M1][1]);              \
    acc[M1][2] = MFMA(A11, b21, acc[M1][2]);              \
    acc[M1][3] = MFMA(A11, b31, acc[M1][3]);

__global__ __launch_bounds__(512, 2) void gemmx2_i8_kernel(const s8* __restrict__ A,
                                                           const s8* __restrict__ B,
                                                           const float* __restrict__ sx,
                                                           const float* __restrict__ scale,
                                                           float* __restrict__ C) {
    __shared__ __align__(16) u8 lds[131072];

#define GLo(src, dstIdx)                                                        \
    __builtin_amdgcn_global_load_lds(                                           \
        (const __attribute__((address_space(1))) void*)(src),                   \
        (__attribute__((address_space(3))) void*)&lds[dstIdx], 16, 0, 0)

    // 256 blocks; XCD-bijective swizzle (256 % 8 == 0)
    int wg = blockIdx.x;
    int swz = (wg & 7) * 32 + (wg >> 3);   // 0..255
    int bn  = swz & 15;                    // 0..15 (shared across both passes)
    int bm0 = (swz >> 4) * 2;              // 0,2,..,30

    int t = threadIdx.x;
    int l = t & 63;
    int wid = t >> 6;
    int wr = wid >> 2;
    int wc = wid & 3;

    const size_t soff = (size_t)(t >> 3) * K_IN + (size_t)((((t & 7) ^ ((t >> 3) & 7)) << 4));
    const size_t S64 = (size_t)64 * K_IN;
    const int t16 = t * 16;

    const s8* Blo = B + (size_t)(bn * 256) * K_IN;
    const s8* Bhi = Blo + (size_t)128 * K_IN;

    const int kx = (l & 7) << 4;
    const int koff0 = (((l >> 4) << 4)) ^ kx;
    const int koff1 = koff0 ^ 64;
    const int aB = wr * 16384 + (l & 15) * 128;
    const int bB = 32768 + wc * 8192 + (l & 15) * 128;

// full prologue stage: tile0 (B,A) -> buf0, B(1) -> buf1, for A-panel base AP
#define PROSTAGE(APlo, APhi)                                                      \
    do {                                                                          \
        GLo(Blo + soff, 32768 + t16);         GLo(Blo + soff + S64, 32768 + t16 + 8192); \
        GLo(Bhi + soff, 49152 + t16);         GLo(Bhi + soff + S64, 49152 + t16 + 8192); \
        GLo((APlo) + soff, t16);              GLo((APlo) + soff + S64, t16 + 8192);      \
        GLo((APhi) + soff, 16384 + t16);      GLo((APhi) + soff + S64, 16384 + t16 + 8192); \
        GLo(Blo + soff + 128, 98304 + t16);   GLo(Blo + soff + S64 + 128, 98304 + t16 + 8192); \
        GLo(Bhi + soff + 128, 114688 + t16);  GLo(Bhi + soff + S64 + 128, 114688 + t16 + 8192); \
    } while (0)

    // initial prologue for pass 0
    {
        const s8* A0lo = A + (size_t)(bm0 * 256) * K_IN;
        const s8* A0hi = A0lo + (size_t)128 * K_IN;
        PROSTAGE(A0lo, A0hi);
    }
    asm volatile("s_waitcnt vmcnt(4)" ::: "memory");
    __builtin_amdgcn_s_barrier();

    for (int p = 0; p < 2; ++p) {
        const int bm = bm0 + p;
        const s8* Alo = A + (size_t)(bm * 256) * K_IN;
        const s8* Ahi = Alo + (size_t)128 * K_IN;

        i32x4 acc[8][4] = {};

        for (int T = 0; T < NT; ++T) {
            const int buf = T & 1;
            const u8* L = lds + buf * 65536;

            // ---- group 1: all B + A m0,m1 ----
            i32x4 b00 = ldsv(L, bB + koff0),        b01 = ldsv(L, bB + koff1);
            i32x4 b10 = ldsv(L, bB + 2048 + koff0), b11 = ldsv(L, bB + 2048 + koff1);
            i32x4 b20 = ldsv(L, bB + 4096 + koff0), b21 = ldsv(L, bB + 4096 + koff1);
            i32x4 b30 = ldsv(L, bB + 6144 + koff0), b31 = ldsv(L, bB + 6144 + koff1);
            i32x4 p00 = ldsv(L, aB + koff0),        p01 = ldsv(L, aB + koff1);
            i32x4 p10 = ldsv(L, aB + 2048 + koff0), p11 = ldsv(L, aB + 2048 + koff1);

            // ---- stage A(T+1) -> other buffer ----
            if (T + 1 < NT) {
                size_t ko = (size_t)(T + 1) * 128;
                int d = (buf ^ 1) * 65536 + t16;
                GLo(Alo + soff + ko, d);                 GLo(Alo + soff + S64 + ko, d + 8192);
                GLo(Ahi + soff + ko, d + 16384);         GLo(Ahi + soff + S64 + ko, d + 24576);
            }

            // ---- read-ahead A m2,m3 ----
            i32x4 q00 = ldsv(L, aB + 4096 + koff0), q01 = ldsv(L, aB + 4096 + koff1);
            i32x4 q10 = ldsv(L, aB + 6144 + koff0), q11 = ldsv(L, aB + 6144 + koff1);

            __builtin_amdgcn_s_setprio(1);
            MFMA16(p00, p01, p10, p11, 0, 1);
            __builtin_amdgcn_s_setprio(0);

            // ---- read-ahead A m4,m5 ----
            p00 = ldsv(L, aB + 8192 + koff0);  p01 = ldsv(L, aB + 8192 + koff1);
            p10 = ldsv(L, aB + 10240 + koff0); p11 = ldsv(L, aB + 10240 + koff1);

            __builtin_amdgcn_s_setprio(1);
            MFMA16(q00, q01, q10, q11, 2, 3);
            __builtin_amdgcn_s_setprio(0);

            // ---- barrier #1: every wave has consumed its B reads ----
            __builtin_amdgcn_s_barrier();
            asm volatile("" ::: "memory");

            if (T + 2 < NT) {
                size_t ko = (size_t)(T + 2) * 128;
                int d = buf * 65536 + 32768 + t16;
                GLo(Blo + soff + ko, d);          GLo(Blo + soff + S64 + ko, d + 8192);
                GLo(Bhi + soff + ko, d + 16384);  GLo(Bhi + soff + S64 + ko, d + 24576);
            }

            // ---- read-ahead A m6,m7 ----
            q00 = ldsv(L, aB + 12288 + koff0); q01 = ldsv(L, aB + 12288 + koff1);
            q10 = ldsv(L, aB + 14336 + koff0); q11 = ldsv(L, aB + 14336 + koff1);

            __builtin_amdgcn_s_setprio(1);
            MFMA16(p00, p01, p10, p11, 4, 5);
            MFMA16(q00, q01, q10, q11, 6, 7);
            __builtin_amdgcn_s_setprio(0);

            // ---- boundary: drain B(T+1)+A(T+1), keep B(T+2) in flight ----
            if (T < NT - 2) asm volatile("s_waitcnt vmcnt(4)" ::: "memory");
            else            asm volatile("s_waitcnt vmcnt(0)" ::: "memory");
            __builtin_amdgcn_s_barrier();
        }

        // ---- pass-0 only: issue pass-1 prologue DMAs (hide under epilogue).
        // All LDS reads of the K-loop completed before its final barrier; the
        // final vmcnt(0) drained all DMAs -> restaging buf0/buf1 is race-free.
        if (p == 0) {
            const s8* A1lo = A + (size_t)((bm0 + 1) * 256) * K_IN;
            const s8* A1hi = A1lo + (size_t)128 * K_IN;
            PROSTAGE(A1lo, A1hi);
        }

        // ---- epilogue for bm ----
        int col0 = bn * 256 + wc * 64 + (l & 15);
        float sc_[4];
#pragma unroll
        for (int n = 0; n < 4; ++n) sc_[n] = scale[col0 + n * 16];

#pragma unroll
        for (int m = 0; m < 8; ++m) {
            int row0 = bm * 256 + wr * 128 + m * 16 + (l >> 4) * 4;
            float4 sxr = *(const float4*)(sx + row0);
            float sxa[4] = {sxr.x, sxr.y, sxr.z, sxr.w};
#pragma unroll
            for (int n = 0; n < 4; ++n) {
                int gcol = col0 + n * 16;
#pragma unroll
                for (int j = 0; j < 4; ++j)
                    C[(size_t)(row0 + j) * N_OUT + gcol] = (float)acc[m][n][j] * sxa[j] * sc_[n];
            }
        }

        if (p == 0) {
            // drain prologue DMAs (and stores) before pass-1 reads buf0
            asm volatile("s_waitcnt vmcnt(0)" ::: "memory");
            __builtin_amdgcn_s_barrier();
        }
    }
#undef PROSTAGE
#undef GLo
}

// ---------------------------------------------------------------------------
// Fallback (workspace too small): fused fp32 LDS-tiled GEMM
// ---------------------------------------------------------------------------
__global__ __launch_bounds__(256) void gemm_fb_kernel(const float* __restrict__ X,
                                                      const int* __restrict__ PW,
                                                      const float* __restrict__ S,
                                                      float* __restrict__ C) {
    __shared__ float sxm[64][33];
    __shared__ float swm[64][33];
    int bm = blockIdx.x / (N_OUT / 64);
    int bn = blockIdx.x % (N_OUT / 64);
    int t = threadIdx.x;
    int r = t >> 2, c8 = (t & 3) * 8;
    int tx = t & 15, ty = t >> 4;
    float acc[4][4] = {};
    for (int k0 = 0; k0 < K_IN; k0 += 32) {
        const float* xs = X + (size_t)(bm * 64 + r) * K_IN + k0 + c8;
#pragma unroll
        for (int j = 0; j < 8; ++j) sxm[r][c8 + j] = xs[j];
        const int* ps = PW + ((size_t)(bn * 64 + r) * K_IN + k0 + c8) / 2;
#pragma unroll
        for (int j = 0; j < 4; ++j) {
            int b = ps[j];
            swm[r][c8 + 2 * j]     = (float)((b & 15) - 8);
            swm[r][c8 + 2 * j + 1] = (float)(((b >> 4) & 15) - 8);
        }
        __syncthreads();
#pragma unroll
        for (int kk = 0; kk < 32; ++kk) {
            float a[4], w[4];
#pragma unroll
            for (int i = 0; i < 4; ++i) a[i] = sxm[ty * 4 + i][kk];
#pragma unroll
            for (int j = 0; j < 4; ++j) w[j] = swm[tx * 4 + j][kk];
#pragma unroll
            for (int i = 0; i < 4; ++i)
#pragma unroll
                for (int j = 0; j < 4; ++j) acc[i][j] += a[i] * w[j];
        }
        __syncthreads();
    }
#pragma unroll
    for (int i = 0; i < 4; ++i) {
        int gr = bm * 64 + ty * 4 + i;
#pragma unroll
        for (int j = 0; j < 4; ++j) {
            int gc = bn * 64 + tx * 4 + j;
            C[(size_t)gr * N_OUT + gc] = acc[i][j] * S[gc];
        }
    }
}

// ---------------------------------------------------------------------------
// Entry point
// ---------------------------------------------------------------------------
extern "C" void kernel_launch(void* const* d_in, const int* in_sizes, int n_in,
                              void* d_out, int out_size, void* d_ws, size_t ws_size,
                              hipStream_t stream) {
    const float* x  = (const float*)d_in[0];
    const int*   pw = (const int*)d_in[1];
    const float* sc = (const float*)d_in[2];
    float* out = (float*)d_out;

    const size_t xq_bytes = (size_t)M_TOK * K_IN;
    const size_t wq_bytes = (size_t)N_OUT * K_IN;
    const size_t sx_bytes = (size_t)M_TOK * sizeof(float);
    const size_t need = xq_bytes + wq_bytes + sx_bytes;

    if (ws_size >= need) {
        s8* xq = (s8*)d_ws;
        s8* wq = xq + xq_bytes;
        float* sx = (float*)(wq + wq_bytes);
        prep_kernel<<<dim3(2560), dim3(256), 0, stream>>>(x, pw, xq, sx, wq);
        gemmx2_i8_kernel<<<dim3(256), dim3(512), 0, stream>>>(xq, wq, sx, sc, out);
    } else {
        gemm_fb_kernel<<<dim3((M_TOK / 64) * (N_OUT / 64)), dim3(256), 0, stream>>>(x, pw, sc, out);
    }
}

// Round 15
// 169.140 us; speedup vs baseline: 1.0115x; 1.0115x over previous
//
#include <hip/hip_runtime.h>

typedef unsigned char u8;
typedef signed char s8;
typedef unsigned int u32;
typedef __attribute__((ext_vector_type(4))) int i32x4;

#define M_TOK 8192
#define N_OUT 4096
#define K_IN  4096
#define NT    32          // K-tiles of BK=128 int8

// ---------------------------------------------------------------------------
// Fused pre-pass (2560 blocks):
//   blocks [0,2048):    wave-per-row absmax quantize x fp32->int8 (4 rows/blk)
//   blocks [2048,2560): unpack int4 (byte-per-int32) -> int8 [O][I]
// ---------------------------------------------------------------------------
static __device__ __forceinline__ u32 pack4(float4 v, float inv) {
    int q0 = __float2int_rn(v.x * inv) & 255;
    int q1 = __float2int_rn(v.y * inv) & 255;
    int q2 = __float2int_rn(v.z * inv) & 255;
    int q3 = __float2int_rn(v.w * inv) & 255;
    return (u32)q0 | ((u32)q1 << 8) | ((u32)q2 << 16) | ((u32)q3 << 24);
}

__global__ __launch_bounds__(256) void prep_kernel(const float* __restrict__ x,
                                                   const int* __restrict__ pw,
                                                   s8* __restrict__ xq,
                                                   float* __restrict__ sx,
                                                   s8* __restrict__ wq) {
    int bid = blockIdx.x;
    int t = threadIdx.x;
    if (bid < 2048) {
        int row = bid * 4 + (t >> 6);
        int ln = t & 63;
        const float4* xr = (const float4*)(x + (size_t)row * K_IN);
        float4 v[16];
        float am = 0.f;
#pragma unroll
        for (int j = 0; j < 16; ++j) {
            v[j] = xr[ln + j * 64];
            am = fmaxf(am, fmaxf(fmaxf(fabsf(v[j].x), fabsf(v[j].y)),
                                 fmaxf(fabsf(v[j].z), fabsf(v[j].w))));
        }
#pragma unroll
        for (int o = 32; o > 0; o >>= 1) am = fmaxf(am, __shfl_xor(am, o));
        float inv = (am > 0.f) ? 127.f / am : 0.f;
        if (ln == 0) sx[row] = (am > 0.f) ? am / 127.f : 0.f;
        u32* out = (u32*)(xq + (size_t)row * K_IN);
#pragma unroll
        for (int j = 0; j < 16; ++j) out[ln + j * 64] = pack4(v[j], inv);
    } else {
        const int n4 = (N_OUT * K_IN / 2) / 4;
        int idx = (bid - 2048) * 256 + t;
        const int stride = 512 * 256;
        for (int i = idx; i < n4; i += stride) {
            int4 p = *(const int4*)(pw + (size_t)i * 4);
            u32 lo = (u32)(((p.x & 15) - 8) & 255)
                   | ((u32)((((p.x >> 4) & 15) - 8) & 255) << 8)
                   | ((u32)((((p.y) & 15) - 8) & 255) << 16)
                   | ((u32)((((p.y >> 4) & 15) - 8) & 255) << 24);
            u32 hi = (u32)(((p.z & 15) - 8) & 255)
                   | ((u32)((((p.z >> 4) & 15) - 8) & 255) << 8)
                   | ((u32)((((p.w) & 15) - 8) & 255) << 16)
                   | ((u32)((((p.w >> 4) & 15) - 8) & 255) << 24);
            uint2 o; o.x = lo; o.y = hi;
            *(uint2*)(wq + (size_t)i * 8) = o;
        }
    }
}

// ---------------------------------------------------------------------------
// 256x256 int8 GEMM (round-9 schedule, verbatim): fine read-ahead interleave,
// counted lgkm via compiler dependency waits, 2 barriers/tile, counted vmcnt.
// C[n][o] = sx[n] * scale[o] * sum_k xq[n][k]*wq[o][k]
// LDS: row-major [256][128] i8 per region, byte ^= (row&7)<<4 swizzle.
// ---------------------------------------------------------------------------
#define MFMA(a, b, c) __builtin_amdgcn_mfma_i32_16x16x64_i8(a, b, c, 0, 0, 0)

static __device__ __forceinline__ i32x4 ldsv(const u8* p, int idx) {
    return *(const i32x4*)(p + idx);
}

#define MFMA16(A00, A01, A10, A11, M0, M1)                \
    acc[M0][0] = MFMA(A00, b00, acc[M0][0]);              \
    acc[M0][1] = MFMA(A00, b10, acc[M0][1]);              \
    acc[M0][2] = MFMA(A00, b20, acc[M0][2]);              \
    acc[M0][3] = MFMA(A00, b30, acc[M0][3]);              \
    acc[M1][0] = MFMA(A10, b00, acc[M1][0]);              \
    acc[M1][1] = MFMA(A10, b10, acc[M1][1]);              \
    acc[M1][2] = MFMA(A10, b20, acc[M1][2]);              \
    acc[M1][3] = MFMA(A10, b30, acc[M1][3]);              \
    acc[M0][0] = MFMA(A01, b01, acc[M0][0]);              \
    acc[M0][1] = MFMA(A01, b11, acc[M0][1]);              \
    acc[M0][2] = MFMA(A01, b21, acc[M0][2]);              \
    acc[M0][3] = MFMA(A01, b31, acc[M0][3]);              \
    acc[M1][0] = MFMA(A11, b01, acc[M1][0]);              \
    acc[M1][1] = MFMA(A11, b11, acc[M1][1]);              \
    acc[M1][2] = MFMA(A11, b21, acc[M1][2]);              \
    acc[M1][3] = MFMA(A11, b31, acc[M1][3]);

__global__ __launch_bounds__(512, 2) void gemmra_i8_kernel(const s8* __restrict__ A,
                                                           const s8* __restrict__ B,
                                                           const float* __restrict__ sx,
                                                           const float* __restrict__ scale,
                                                           float* __restrict__ C) {
    __shared__ __align__(16) u8 lds[131072];

#define GLo(src, dstIdx)                                                        \
    __builtin_amdgcn_global_load_lds(                                           \
        (const __attribute__((address_space(1))) void*)(src),                   \
        (__attribute__((address_space(3))) void*)&lds[dstIdx], 16, 0, 0)

    int wg = blockIdx.x;
    int swz = (wg & 7) * 64 + (wg >> 3);
    int bm = swz >> 4;
    int bn = swz & 15;

    int t = threadIdx.x;
    int l = t & 63;
    int wid = t >> 6;
    int wr = wid >> 2;
    int wc = wid & 3;

    const size_t soff = (size_t)(t >> 3) * K_IN + (size_t)((((t & 7) ^ ((t >> 3) & 7)) << 4));
    const size_t S64 = (size_t)64 * K_IN;
    const int t16 = t * 16;

    const s8* Alo = A + (size_t)(bm * 256) * K_IN;
    const s8* Ahi = Alo + (size_t)128 * K_IN;
    const s8* Blo = B + (size_t)(bn * 256) * K_IN;
    const s8* Bhi = Blo + (size_t)128 * K_IN;

    const int kx = (l & 7) << 4;
    const int koff0 = (((l >> 4) << 4)) ^ kx;
    const int koff1 = koff0 ^ 64;
    const int aB = wr * 16384 + (l & 15) * 128;
    const int bB = 32768 + wc * 8192 + (l & 15) * 128;

    i32x4 acc[8][4] = {};

    // ---- prologue: B(0),A(0) -> buf0; B(1) -> buf1 ----
    GLo(Blo + soff, 32768 + t16);         GLo(Blo + soff + S64, 32768 + t16 + 8192);
    GLo(Bhi + soff, 49152 + t16);         GLo(Bhi + soff + S64, 49152 + t16 + 8192);
    GLo(Alo + soff, t16);                 GLo(Alo + soff + S64, t16 + 8192);
    GLo(Ahi + soff, 16384 + t16);         GLo(Ahi + soff + S64, 16384 + t16 + 8192);
    GLo(Blo + soff + 128, 98304 + t16);   GLo(Blo + soff + S64 + 128, 98304 + t16 + 8192);
    GLo(Bhi + soff + 128, 114688 + t16);  GLo(Bhi + soff + S64 + 128, 114688 + t16 + 8192);
    asm volatile("s_waitcnt vmcnt(4)" ::: "memory");
    __builtin_amdgcn_s_barrier();

    for (int T = 0; T < NT; ++T) {
        const int buf = T & 1;
        const u8* L = lds + buf * 65536;

        // ---- group 1: all B + A m0,m1 ----
        i32x4 b00 = ldsv(L, bB + koff0),        b01 = ldsv(L, bB + koff1);
        i32x4 b10 = ldsv(L, bB + 2048 + koff0), b11 = ldsv(L, bB + 2048 + koff1);
        i32x4 b20 = ldsv(L, bB + 4096 + koff0), b21 = ldsv(L, bB + 4096 + koff1);
        i32x4 b30 = ldsv(L, bB + 6144 + koff0), b31 = ldsv(L, bB + 6144 + koff1);
        i32x4 p00 = ldsv(L, aB + koff0),        p01 = ldsv(L, aB + koff1);
        i32x4 p10 = ldsv(L, aB + 2048 + koff0), p11 = ldsv(L, aB + 2048 + koff1);

        // ---- stage A(T+1) -> other buffer ----
        if (T + 1 < NT) {
            size_t ko = (size_t)(T + 1) * 128;
            int d = (buf ^ 1) * 65536 + t16;
            GLo(Alo + soff + ko, d);                 GLo(Alo + soff + S64 + ko, d + 8192);
            GLo(Ahi + soff + ko, d + 16384);         GLo(Ahi + soff + S64 + ko, d + 24576);
        }

        // ---- read-ahead A m2,m3 (in flight under MFMA m0,m1) ----
        i32x4 q00 = ldsv(L, aB + 4096 + koff0), q01 = ldsv(L, aB + 4096 + koff1);
        i32x4 q10 = ldsv(L, aB + 6144 + koff0), q11 = ldsv(L, aB + 6144 + koff1);

        __builtin_amdgcn_s_setprio(1);
        MFMA16(p00, p01, p10, p11, 0, 1);
        __builtin_amdgcn_s_setprio(0);

        // ---- read-ahead A m4,m5 ----
        p00 = ldsv(L, aB + 8192 + koff0);  p01 = ldsv(L, aB + 8192 + koff1);
        p10 = ldsv(L, aB + 10240 + koff0); p11 = ldsv(L, aB + 10240 + koff1);

        __builtin_amdgcn_s_setprio(1);
        MFMA16(q00, q01, q10, q11, 2, 3);
        __builtin_amdgcn_s_setprio(0);

        // ---- barrier #1: every wave has consumed its B reads ----
        __builtin_amdgcn_s_barrier();
        asm volatile("" ::: "memory");

        if (T + 2 < NT) {
            size_t ko = (size_t)(T + 2) * 128;
            int d = buf * 65536 + 32768 + t16;
            GLo(Blo + soff + ko, d);          GLo(Blo + soff + S64 + ko, d + 8192);
            GLo(Bhi + soff + ko, d + 16384);  GLo(Bhi + soff + S64 + ko, d + 24576);
        }

        // ---- read-ahead A m6,m7 ----
        q00 = ldsv(L, aB + 12288 + koff0); q01 = ldsv(L, aB + 12288 + koff1);
        q10 = ldsv(L, aB + 14336 + koff0); q11 = ldsv(L, aB + 14336 + koff1);

        __builtin_amdgcn_s_setprio(1);
        MFMA16(p00, p01, p10, p11, 4, 5);
        MFMA16(q00, q01, q10, q11, 6, 7);
        __builtin_amdgcn_s_setprio(0);

        // ---- boundary: drain B(T+1)+A(T+1), keep B(T+2) in flight ----
        if (T < NT - 2) asm volatile("s_waitcnt vmcnt(4)" ::: "memory");
        else            asm volatile("s_waitcnt vmcnt(0)" ::: "memory");
        __builtin_amdgcn_s_barrier();
    }

    // ---- epilogue ----
    int col0 = bn * 256 + wc * 64 + (l & 15);
    float sc_[4];
#pragma unroll
    for (int n = 0; n < 4; ++n) sc_[n] = scale[col0 + n * 16];

#pragma unroll
    for (int m = 0; m < 8; ++m) {
        int row0 = bm * 256 + wr * 128 + m * 16 + (l >> 4) * 4;
        float4 sxr = *(const float4*)(sx + row0);
        float sxa[4] = {sxr.x, sxr.y, sxr.z, sxr.w};
#pragma unroll
        for (int n = 0; n < 4; ++n) {
            int gcol = col0 + n * 16;
#pragma unroll
            for (int j = 0; j < 4; ++j)
                C[(size_t)(row0 + j) * N_OUT + gcol] = (float)acc[m][n][j] * sxa[j] * sc_[n];
        }
    }
#undef GLo
}

// ---------------------------------------------------------------------------
// Fallback (workspace too small): fused fp32 LDS-tiled GEMM
// ---------------------------------------------------------------------------
__global__ __launch_bounds__(256) void gemm_fb_kernel(const float* __restrict__ X,
                                                      const int* __restrict__ PW,
                                                      const float* __restrict__ S,
                                                      float* __restrict__ C) {
    __shared__ float sxm[64][33];
    __shared__ float swm[64][33];
    int bm = blockIdx.x / (N_OUT / 64);
    int bn = blockIdx.x % (N_OUT / 64);
    int t = threadIdx.x;
    int r = t >> 2, c8 = (t & 3) * 8;
    int tx = t & 15, ty = t >> 4;
    float acc[4][4] = {};
    for (int k0 = 0; k0 < K_IN; k0 += 32) {
        const float* xs = X + (size_t)(bm * 64 + r) * K_IN + k0 + c8;
#pragma unroll
        for (int j = 0; j < 8; ++j) sxm[r][c8 + j] = xs[j];
        const int* ps = PW + ((size_t)(bn * 64 + r) * K_IN + k0 + c8) / 2;
#pragma unroll
        for (int j = 0; j < 4; ++j) {
            int b = ps[j];
            swm[r][c8 + 2 * j]     = (float)((b & 15) - 8);
            swm[r][c8 + 2 * j + 1] = (float)(((b >> 4) & 15) - 8);
        }
        __syncthreads();
#pragma unroll
        for (int kk = 0; kk < 32; ++kk) {
            float a[4], w[4];
#pragma unroll
            for (int i = 0; i < 4; ++i) a[i] = sxm[ty * 4 + i][kk];
#pragma unroll
            for (int j = 0; j < 4; ++j) w[j] = swm[tx * 4 + j][kk];
#pragma unroll
            for (int i = 0; i < 4; ++i)
#pragma unroll
                for (int j = 0; j < 4; ++j) acc[i][j] += a[i] * w[j];
        }
        __syncthreads();
    }
#pragma unroll
    for (int i = 0; i < 4; ++i) {
        int gr = bm * 64 + ty * 4 + i;
#pragma unroll
        for (int j = 0; j < 4; ++j) {
            int gc = bn * 64 + tx * 4 + j;
            C[(size_t)gr * N_OUT + gc] = acc[i][j] * S[gc];
        }
    }
}

// ---------------------------------------------------------------------------
// Entry point
// ---------------------------------------------------------------------------
extern "C" void kernel_launch(void* const* d_in, const int* in_sizes, int n_in,
                              void* d_out, int out_size, void* d_ws, size_t ws_size,
                              hipStream_t stream) {
    const float* x  = (const float*)d_in[0];
    const int*   pw = (const int*)d_in[1];
    const float* sc = (const float*)d_in[2];
    float* out = (float*)d_out;

    const size_t xq_bytes = (size_t)M_TOK * K_IN;
    const size_t wq_bytes = (size_t)N_OUT * K_IN;
    const size_t sx_bytes = (size_t)M_TOK * sizeof(float);
    const size_t need = xq_bytes + wq_bytes + sx_bytes;

    if (ws_size >= need) {
        s8* xq = (s8*)d_ws;
        s8* wq = xq + xq_bytes;
        float* sx = (float*)(wq + wq_bytes);
        prep_kernel<<<dim3(2560), dim3(256), 0, stream>>>(x, pw, xq, sx, wq);
        gemmra_i8_kernel<<<dim3((M_TOK / 256) * (N_OUT / 256)), dim3(512), 0, stream>>>(
            xq, wq, sx, sc, out);
    } else {
        gemm_fb_kernel<<<dim3((M_TOK / 64) * (N_OUT / 64)), dim3(256), 0, stream>>>(x, pw, sc, out);
    }
}